// Round 9
// baseline (16584.019 us; speedup 1.0000x reference)
//
#include <hip/hip_runtime.h>
#include <hip/hip_bf16.h>

#define B_ 64
#define T_ 1024
#define D_ 512
#define H_ 512
#define O_ 512
#define NBLK 32        // recurrence blocks
#define NHEAT 224      // heater blocks (pure FMA, keep clocks up)
#define FSTR 32        // flag stride in u32 (one 128-B line per flag)

using bf16x8 = __attribute__((ext_vector_type(8))) short;
using f32x4  = __attribute__((ext_vector_type(4))) float;
using u32x4  = __attribute__((ext_vector_type(4))) unsigned int;

__device__ __forceinline__ short f2bfs(float f) {
  return (short)__builtin_bit_cast(unsigned short, __float2bfloat16(f));
}
__device__ __forceinline__ float sigmoid_f(float v) {
  return 1.0f / (1.0f + __expf(-v));
}
__device__ __forceinline__ float tanh_f(float v) {
  float a = fabsf(v);
  float e = __expf(-2.0f * a);
  float t = (1.0f - e) / (1.0f + e);
  return copysignf(t, v);
}

// ---------------------------------------------------------------------------
// Setup: pack W_all (1024x2048) and W_hy (512x512) into MFMA B-fragment order
// (bf16), convert h_init into the BLOCK-SLICED hpub layout, zero flags.
// hpub layout: hpub[jb][b][c] (jb 0..31 slice of 16 cols, b 0..63, c 0..15)
// ---------------------------------------------------------------------------
__global__ __launch_bounds__(256) void pack_setup(
    const float* __restrict__ Wf, const float* __restrict__ Wi,
    const float* __restrict__ Wc, const float* __restrict__ Wo,
    const float* __restrict__ Why, const float* __restrict__ hinit,
    unsigned short* __restrict__ Wp, unsigned short* __restrict__ Whyp,
    unsigned short* __restrict__ hbf0, unsigned int* __restrict__ flg)
{
  long idx = (long)blockIdx.x * blockDim.x + threadIdx.x;
  if (idx < NBLK * FSTR) flg[idx] = 0u;        // re-zeroed every call
  const long NW = 1024L * 2048;
  const long NY = 512L * 512;
  const long NH = 64L * 512;
  if (idx < NW) {
    int e = idx & 7, l = (idx >> 3) & 63, kk = (idx >> 9) & 31;
    int Jc = (int)(idx >> 14);                   // 0..127
    int k = kk * 32 + (l >> 4) * 8 + e;          // 0..1023
    int col = Jc * 16 + (l & 15);                // 0..2047
    int gg = col >> 9, j = col & 511;
    const float* W = (gg == 0) ? Wf : (gg == 1) ? Wi : (gg == 2) ? Wc : Wo;
    Wp[idx] = (unsigned short)f2bfs(W[(long)k * 512 + j]);
  } else if (idx < NW + NY) {
    long q = idx - NW;
    int e = q & 7, l = (q >> 3) & 63, kk = (q >> 9) & 15;
    int J = (int)(q >> 13);
    int k = kk * 32 + (l >> 4) * 8 + e;
    int col = J * 16 + (l & 15);
    Whyp[q] = (unsigned short)f2bfs(Why[(long)k * 512 + col]);
  } else if (idx < NW + NY + NH) {
    long q = idx - NW - NY;                      // hpub layout index
    int jb = (int)(q >> 10), b = (int)((q >> 4) & 63), c = (int)(q & 15);
    hbf0[q] = (unsigned short)f2bfs(hinit[(long)b * 512 + jb * 16 + c]);
  }
}

// ---------------------------------------------------------------------------
// x fp32 -> bf16 streaming conversion.
// ---------------------------------------------------------------------------
__global__ __launch_bounds__(256) void xconv(
    const float* __restrict__ x, unsigned short* __restrict__ xb)
{
  long i = ((long)blockIdx.x * 256 + threadIdx.x) * 8;
  float4 a = *(const float4*)(x + i);
  float4 b = *(const float4*)(x + i + 4);
  bf16x8 v;
  v[0] = f2bfs(a.x); v[1] = f2bfs(a.y); v[2] = f2bfs(a.z); v[3] = f2bfs(a.w);
  v[4] = f2bfs(b.x); v[5] = f2bfs(b.y); v[6] = f2bfs(b.z); v[7] = f2bfs(b.w);
  *(bf16x8*)(xb + i) = v;
}

// ---------------------------------------------------------------------------
// Recurrence + heaters. 256 blocks x 256 threads, 1 block/CU guaranteed by
// VGPR ballast (>256 regs -> 1 wave/SIMD).
// Blocks 0..31: proven R8 data path, EXCEPT h publish goes through LDS and
//   out as 2 full-128B-line dwordx4 sc0|sc1 stores (hpub block-sliced layout);
//   consumer h loads are coalesced 16B sc0|sc1 loads of that layout.
// Blocks 32..255: dependent-FMA heaters; poll exit flags 1x per ~8k cycles.
// ---------------------------------------------------------------------------
template<bool X16>
__global__ __attribute__((amdgpu_waves_per_eu(1, 1))) __launch_bounds__(256)
void lstm_seq(
    const void* __restrict__ xv,      // (B,T,D) bf16 or fp32
    const float* __restrict__ cinit,  // (B,H)
    const float* __restrict__ bf_, const float* __restrict__ bi_,
    const float* __restrict__ bc_, const float* __restrict__ bo_,
    const unsigned short* __restrict__ Wp,
    unsigned short* __restrict__ hpub0,   // [32][64][16] bf16 (2KB/block)
    unsigned short* __restrict__ hpub1,
    unsigned short* __restrict__ hs,      // [T][32][64][16] bf16
    float* __restrict__ tail,             // d_out + B*T*O : h_fin then c_fin
    unsigned int* __restrict__ flg)
{
  __shared__ unsigned short hstage[1024];   // [64 rows][16 cols] = 2KB

  const int bid  = blockIdx.x;
  const int tid  = threadIdx.x;
  const int wv   = tid >> 6;
  const int lane = tid & 63;
  const int lrow = lane & 15;
  const int lkg  = lane >> 4;

  // VGPR ballast: 24 live f32x4 = 96 regs on top of the ~180 natural ->
  // >256 total -> 1 wave/SIMD -> 1 block/CU (heaters never share with real).
  f32x4 pad[24];
  #pragma unroll
  for (int i = 0; i < 24; ++i) pad[i] = {0.f, 0.f, 0.f, 0.f};
  #define KEEPPADS() do { \
    asm volatile("" : "+v"(pad[0]), "+v"(pad[1]), "+v"(pad[2]), "+v"(pad[3])); \
    asm volatile("" : "+v"(pad[4]), "+v"(pad[5]), "+v"(pad[6]), "+v"(pad[7])); \
    asm volatile("" : "+v"(pad[8]), "+v"(pad[9]), "+v"(pad[10]), "+v"(pad[11])); \
    asm volatile("" : "+v"(pad[12]), "+v"(pad[13]), "+v"(pad[14]), "+v"(pad[15])); \
    asm volatile("" : "+v"(pad[16]), "+v"(pad[17]), "+v"(pad[18]), "+v"(pad[19])); \
    asm volatile("" : "+v"(pad[20]), "+v"(pad[21]), "+v"(pad[22]), "+v"(pad[23])); \
  } while (0)

  if (bid >= NBLK) {
    // ===================== heater =====================
    float burn = (float)(tid + 1) * 1e-3f;
    const unsigned int* fp = flg + (lane & 31) * FSTR;
    #pragma unroll 1
    for (int it = 0; it < 4000; ++it) {
      KEEPPADS();
      #pragma unroll 8
      for (int u = 0; u < 2048; ++u) burn = __builtin_fmaf(burn, 1.0000002f, 1e-9f);
      asm volatile("" : "+v"(burn));
      unsigned f;
      asm volatile("global_load_dword %0, %1, off sc0 sc1\n\ts_waitcnt vmcnt(0)"
                   : "=v"(f) : "v"(fp) : "memory");
      if (__all((int)f >= T_)) break;
    }
    if (burn == 1.2345e30f) tail[0] = burn;   // keep live; never true
    return;
  }

  // ===================== recurrence block =====================
  const int jb   = bid;
  const int b_arow = wv * 16 + lrow;       // A-fragment row (batch index)
  const int jcol   = jb * 16 + lrow;       // owned hidden unit
  const int b_cd0  = wv * 16 + lkg * 4;    // C/D row base

  const float vbf = bf_[jcol], vbi = bi_[jcol], vbc = bc_[jcol], vbo = bo_[jcol];
  float c0 = cinit[(long)(b_cd0 + 0) * H_ + jcol];
  float c1 = cinit[(long)(b_cd0 + 1) * H_ + jcol];
  float c2 = cinit[(long)(b_cd0 + 2) * H_ + jcol];
  float c3 = cinit[(long)(b_cd0 + 3) * H_ + jcol];

  const unsigned short* xrow16 = X16 ? (const unsigned short*)xv + (long)b_arow * T_ * D_ + lkg * 8 : nullptr;
  const float*          xrow32 = X16 ? nullptr : (const float*)xv + (long)b_arow * T_ * D_ + lkg * 8;
  const unsigned short* w0 = Wp + (long)(0 * 32 + jb) * 32 * 512 + lane * 8;
  const unsigned short* w1 = Wp + (long)(1 * 32 + jb) * 32 * 512 + lane * 8;
  const unsigned short* w2 = Wp + (long)(2 * 32 + jb) * 32 * 512 + lane * 8;
  const unsigned short* w3 = Wp + (long)(3 * 32 + jb) * 32 * 512 + lane * 8;

  // h A-frag address pieces (hpub layout): addr = (2kk + (lkg>>1))*1024 + b_arow*16 + (lkg&1)*8
  const long hoff = (long)(lkg >> 1) * 1024 + (long)b_arow * 16 + (lkg & 1) * 8;

  bf16x8 xf[16];
  float4 xr[32];
  if constexpr (X16) {
    #pragma unroll
    for (int kk = 0; kk < 16; ++kk) xf[kk] = *(const bf16x8*)(xrow16 + kk * 32);
  } else {
    #pragma unroll
    for (int kk = 0; kk < 16; ++kk) {
      xr[2*kk]   = *(const float4*)(xrow32 + kk * 32);
      xr[2*kk+1] = *(const float4*)(xrow32 + kk * 32 + 4);
    }
  }

  #pragma unroll 1
  for (int t = 0; t < T_; ++t) {
    KEEPPADS();
    // ---- x half of GEMM (k 512..1023) before the poll ----
    f32x4 af = {vbf, vbf, vbf, vbf};
    f32x4 ai = {vbi, vbi, vbi, vbi};
    f32x4 ac = {vbc, vbc, vbc, vbc};
    f32x4 ao = {vbo, vbo, vbo, vbo};
    #pragma unroll
    for (int kk = 0; kk < 16; ++kk) {
      bf16x8 ax;
      if constexpr (X16) {
        ax = xf[kk];
      } else {
        float4 xa = xr[2*kk], xb2 = xr[2*kk+1];
        ax[0]=f2bfs(xa.x); ax[1]=f2bfs(xa.y); ax[2]=f2bfs(xa.z); ax[3]=f2bfs(xa.w);
        ax[4]=f2bfs(xb2.x); ax[5]=f2bfs(xb2.y); ax[6]=f2bfs(xb2.z); ax[7]=f2bfs(xb2.w);
      }
      const int k2 = kk + 16;
      af = __builtin_amdgcn_mfma_f32_16x16x32_bf16(ax, *(const bf16x8*)(w0 + k2 * 512), af, 0, 0, 0);
      ai = __builtin_amdgcn_mfma_f32_16x16x32_bf16(ax, *(const bf16x8*)(w1 + k2 * 512), ai, 0, 0, 0);
      ac = __builtin_amdgcn_mfma_f32_16x16x32_bf16(ax, *(const bf16x8*)(w2 + k2 * 512), ac, 0, 0, 0);
      ao = __builtin_amdgcn_mfma_f32_16x16x32_bf16(ax, *(const bf16x8*)(w3 + k2 * 512), ao, 0, 0, 0);
    }

    // ---- handoff wait: wave0 polls private flag lines ----
    if (wv == 0) {
      const unsigned tgt = (unsigned)t;
      const unsigned int* fp = flg + (lane & 31) * FSTR;
      int guard = 0;
      for (;;) {
        unsigned f;
        asm volatile("global_load_dword %0, %1, off sc0 sc1\n\ts_waitcnt vmcnt(0)"
                     : "=v"(f) : "v"(fp) : "memory");
        if (__all((int)(f >= tgt))) break;
        if (++guard > (1 << 20)) break;
        __builtin_amdgcn_s_sleep(2);
      }
    }
    __syncthreads();
    asm volatile("" ::: "memory");

    // ---- h loads: coalesced 16B sc0|sc1 from hpub layout ----
    const unsigned short* hq = (t & 1) ? hpub1 : hpub0;
    u32x4 hu[16];
    #pragma unroll
    for (int kk = 0; kk < 16; ++kk) {
      const unsigned short* p = hq + (long)(2 * kk) * 1024 + hoff;
      asm volatile("global_load_dwordx4 %0, %1, off sc0 sc1" : "=v"(hu[kk]) : "v"(p));
    }
    asm volatile("s_waitcnt vmcnt(0)" ::: "memory");
    __builtin_amdgcn_sched_barrier(0);

    // ---- h half of GEMM (k 0..511) ----
    #pragma unroll
    for (int kk = 0; kk < 16; ++kk) {
      bf16x8 ah = __builtin_bit_cast(bf16x8, hu[kk]);
      af = __builtin_amdgcn_mfma_f32_16x16x32_bf16(ah, *(const bf16x8*)(w0 + kk * 512), af, 0, 0, 0);
      ai = __builtin_amdgcn_mfma_f32_16x16x32_bf16(ah, *(const bf16x8*)(w1 + kk * 512), ai, 0, 0, 0);
      ac = __builtin_amdgcn_mfma_f32_16x16x32_bf16(ah, *(const bf16x8*)(w2 + kk * 512), ac, 0, 0, 0);
      ao = __builtin_amdgcn_mfma_f32_16x16x32_bf16(ah, *(const bf16x8*)(w3 + kk * 512), ao, 0, 0, 0);
    }

    // ---- gates + state update; stage h slice in LDS ----
    float hvf[4], cvf[4];
    #pragma unroll
    for (int i2 = 0; i2 < 4; ++i2) {
      float fg = sigmoid_f(af[i2]);
      float ig = sigmoid_f(ai[i2]);
      float gg2 = tanh_f(ac[i2]);
      float og = sigmoid_f(ao[i2]);
      float cN = (i2 == 0) ? c0 : (i2 == 1) ? c1 : (i2 == 2) ? c2 : c3;
      cN = fg * cN + ig * gg2;
      float hv = og * tanh_f(cN);
      if (i2 == 0) c0 = cN; else if (i2 == 1) c1 = cN; else if (i2 == 2) c2 = cN; else c3 = cN;
      hvf[i2] = hv; cvf[i2] = cN;
      hstage[(b_cd0 + i2) * 16 + lrow] = (unsigned short)f2bfs(hv);
    }
    __syncthreads();

    // ---- wave0: full-line publish (2 x dwordx4 sc0|sc1), drain, flag ----
    if (wv == 0) {
      u32x4 d0 = *(const u32x4*)((const char*)hstage + lane * 16);
      u32x4 d1 = *(const u32x4*)((const char*)hstage + 1024 + lane * 16);
      unsigned short* hw = (t & 1) ? hpub0 : hpub1;
      char* pub = (char*)hw + (long)jb * 2048 + lane * 16;
      asm volatile("global_store_dwordx4 %0, %1, off sc0 sc1" :: "v"(pub), "v"(d0) : "memory");
      asm volatile("global_store_dwordx4 %0, %1, off sc0 sc1" :: "v"(pub + 1024), "v"(d1) : "memory");
      asm volatile("s_waitcnt vmcnt(0)" ::: "memory");
      if (lane == 0) {
        unsigned v = (unsigned)(t + 1);
        unsigned int* p2 = flg + jb * FSTR;
        asm volatile("global_store_dword %0, %1, off sc0 sc1" :: "v"(p2), "v"(v) : "memory");
      }
      // hs history (same block-sliced layout), off critical path
      char* hsp = (char*)hs + (long)t * 65536 + (long)jb * 2048 + lane * 16;
      *(u32x4*)hsp = d0;
      *(u32x4*)(hsp + 1024) = d1;
    }

    // ---- off-critical-path: tail + next-x prefetch ----
    if (t == T_ - 1) {
      #pragma unroll
      for (int i2 = 0; i2 < 4; ++i2) {
        int brow = b_cd0 + i2;
        tail[(long)brow * H_ + jcol] = hvf[i2];
        tail[(long)B_ * H_ + (long)brow * H_ + jcol] = cvf[i2];
      }
    }
    const long tn = (t + 1 < T_) ? (t + 1) : t;
    if constexpr (X16) {
      const unsigned short* xt = xrow16 + tn * D_;
      #pragma unroll
      for (int kk = 0; kk < 16; ++kk) xf[kk] = *(const bf16x8*)(xt + kk * 32);
    } else {
      const float* xt = xrow32 + tn * D_;
      #pragma unroll
      for (int kk = 0; kk < 16; ++kk) {
        xr[2*kk]   = *(const float4*)(xt + kk * 32);
        xr[2*kk+1] = *(const float4*)(xt + kk * 32 + 4);
      }
    }
  }
  #undef KEEPPADS
}

// ---------------------------------------------------------------------------
// Output projection from block-sliced hs: out(B,T,O) = hs @ W_hy + b_hy.
// hs element (t, b, k) at shorts: t*32768 + (k>>4)*1024 + b*16 + (k&15).
// ---------------------------------------------------------------------------
__global__ __launch_bounds__(512) void out_proj(
    const unsigned short* __restrict__ hs,
    const unsigned short* __restrict__ Whyp,
    const float* __restrict__ bhy,
    float* __restrict__ out)
{
  const int tid  = threadIdx.x;
  const int wv   = tid >> 6;
  const int lane = tid & 63;
  const int lrow = lane & 15;
  const int lkg  = lane >> 4;
  const int mg = wv >> 2;
  const int ng = wv & 3;
  const long mbase = (long)blockIdx.x * 128 + mg * 64;
  const int  t0 = (int)(mbase >> 6);           // one timestep per 64-row group

  f32x4 acc[4][8];
  #pragma unroll
  for (int mt = 0; mt < 4; ++mt)
    #pragma unroll
    for (int nt = 0; nt < 8; ++nt) {
      float b = bhy[ng * 128 + nt * 16 + lrow];
      acc[mt][nt] = {b, b, b, b};
    }

  // A addr: t0*32768 + (2kk + (lkg>>1))*1024 + (mt*16+lrow)*16 + (lkg&1)*8
  const unsigned short* abase = hs + (long)t0 * 32768 + (long)(lkg >> 1) * 1024
                                   + (long)lrow * 16 + (lkg & 1) * 8;
  const unsigned short* bbas = Whyp + (long)(ng * 8) * 8192 + lane * 8;

  #pragma unroll
  for (int kk = 0; kk < 16; ++kk) {
    const unsigned short* ak = abase + (long)(2 * kk) * 1024;
    bf16x8 a0 = *(const bf16x8*)(ak + 0 * 256);    // mt*16 rows * 16 shorts
    bf16x8 a1 = *(const bf16x8*)(ak + 1 * 256);
    bf16x8 a2 = *(const bf16x8*)(ak + 2 * 256);
    bf16x8 a3 = *(const bf16x8*)(ak + 3 * 256);
    #pragma unroll
    for (int nt = 0; nt < 8; ++nt) {
      bf16x8 bv = *(const bf16x8*)(bbas + nt * 8192 + kk * 512);
      acc[0][nt] = __builtin_amdgcn_mfma_f32_16x16x32_bf16(a0, bv, acc[0][nt], 0, 0, 0);
      acc[1][nt] = __builtin_amdgcn_mfma_f32_16x16x32_bf16(a1, bv, acc[1][nt], 0, 0, 0);
      acc[2][nt] = __builtin_amdgcn_mfma_f32_16x16x32_bf16(a2, bv, acc[2][nt], 0, 0, 0);
      acc[3][nt] = __builtin_amdgcn_mfma_f32_16x16x32_bf16(a3, bv, acc[3][nt], 0, 0, 0);
    }
  }

  #pragma unroll
  for (int mt = 0; mt < 4; ++mt) {
    #pragma unroll
    for (int i2 = 0; i2 < 4; ++i2) {
      long m = mbase + mt * 16 + lkg * 4 + i2;
      long t = m >> 6, b = m & 63;
      float* orow = out + (b * 1024 + t) * 512;
      #pragma unroll
      for (int nt = 0; nt < 8; ++nt)
        orow[ng * 128 + nt * 16 + lrow] = acc[mt][nt][i2];
    }
  }
}

// ---------------------------------------------------------------------------
extern "C" void kernel_launch(void* const* d_in, const int* in_sizes, int n_in,
                              void* d_out, int out_size, void* d_ws, size_t ws_size,
                              hipStream_t stream) {
  const float* x      = (const float*)d_in[0];
  const float* h_init = (const float*)d_in[1];
  const float* c_init = (const float*)d_in[2];
  const float* W_f = (const float*)d_in[3];
  const float* b_f = (const float*)d_in[4];
  const float* W_i = (const float*)d_in[5];
  const float* b_i = (const float*)d_in[6];
  const float* W_c = (const float*)d_in[7];
  const float* b_c = (const float*)d_in[8];
  const float* W_o = (const float*)d_in[9];
  const float* b_o = (const float*)d_in[10];
  const float* W_hy = (const float*)d_in[11];
  const float* b_hy = (const float*)d_in[12];
  float* out = (float*)d_out;

  // ws layout (bytes)
  const size_t WP_OFF   = 0;                          // 4 MB
  const size_t WHYP_OFF = 4u << 20;                   // 512 KB
  const size_t HP0_OFF  = WHYP_OFF + (512u << 10);    // 64 KB
  const size_t HP1_OFF  = HP0_OFF + (64u << 10);      // 64 KB
  const size_t FLG_OFF  = HP1_OFF + (64u << 10);      // 4 KB strided flags
  const size_t XB_OFF   = 8u << 20;                   // 64 MB (big path only)
  const size_t HS_BYTES = (size_t)T_ * B_ * H_ * 2;   // 64 MB
  const size_t XB_BYTES = (size_t)B_ * T_ * D_ * 2;   // 64 MB
  const size_t NEED_SMALL = (8u << 20) + HS_BYTES;
  const size_t NEED_BIG   = XB_OFF + XB_BYTES + HS_BYTES;
  if (ws_size < NEED_SMALL) return;
  const bool big = (ws_size >= NEED_BIG);

  unsigned char* w = (unsigned char*)d_ws;
  unsigned short* Wp   = (unsigned short*)(w + WP_OFF);
  unsigned short* Whyp = (unsigned short*)(w + WHYP_OFF);
  unsigned short* hp0  = (unsigned short*)(w + HP0_OFF);
  unsigned short* hp1  = (unsigned short*)(w + HP1_OFF);
  unsigned int*   flg  = (unsigned int*)(w + FLG_OFF);
  unsigned short* xb   = (unsigned short*)(w + XB_OFF);
  unsigned short* hs   = (unsigned short*)(w + (big ? XB_OFF + XB_BYTES : (size_t)(8u << 20)));

  // 1) pack weights + init + flag zeroing
  const long total = 1024L * 2048 + 512L * 512 + 64L * 512;
  int pgrid = (int)((total + 255) / 256);
  pack_setup<<<pgrid, 256, 0, stream>>>(W_f, W_i, W_c, W_o, W_hy, h_init,
                                        Wp, Whyp, hp0, flg);

  // 2) optional x -> bf16 preconversion
  if (big) {
    const long nx = (long)B_ * T_ * D_;
    int xgrid = (int)(nx / (256 * 8));
    xconv<<<xgrid, 256, 0, stream>>>(x, xb);
  }

  // 3) recurrence + heaters (256 blocks, 1/CU)
  float* tail = out + (size_t)B_ * T_ * O_;
  if (big) {
    lstm_seq<true><<<NBLK + NHEAT, 256, 0, stream>>>(
        xb, c_init, b_f, b_i, b_c, b_o, Wp, hp0, hp1, hs, tail, flg);
  } else {
    lstm_seq<false><<<NBLK + NHEAT, 256, 0, stream>>>(
        x, c_init, b_f, b_i, b_c, b_o, Wp, hp0, hp1, hs, tail, flg);
  }

  // 4) output projection (block-sliced hs layout)
  out_proj<<<512, 512, 0, stream>>>(hs, Whyp, b_hy, out);
}

// Round 10
// 11160.809 us; speedup vs baseline: 1.4859x; 1.4859x over previous
//
#include <hip/hip_runtime.h>
#include <hip/hip_bf16.h>

#define B_ 64
#define T_ 1024
#define D_ 512
#define H_ 512
#define O_ 512
#define NBLK 32   // j-slice blocks per step kernel

using bf16x8 = __attribute__((ext_vector_type(8))) short;
using f32x4  = __attribute__((ext_vector_type(4))) float;

__device__ __forceinline__ short f2bfs(float f) {
  return (short)__builtin_bit_cast(unsigned short, __float2bfloat16(f));
}
__device__ __forceinline__ float sigmoid_f(float v) {
  return 1.0f / (1.0f + __expf(-v));
}
__device__ __forceinline__ float tanh_f(float v) {
  float a = fabsf(v);
  float e = __expf(-2.0f * a);
  float t = (1.0f - e) / (1.0f + e);
  return copysignf(t, v);
}

// ---------------------------------------------------------------------------
// Setup: pack W_all (1024x2048) and W_hy (512x512) into MFMA B-fragment order
// (bf16), convert h_init to bf16 (h buffer 0), copy c_init into fp32 cbuf.
// Re-runs every call -> stateless across graph replays.
// ---------------------------------------------------------------------------
__global__ __launch_bounds__(256) void pack_setup(
    const float* __restrict__ Wf, const float* __restrict__ Wi,
    const float* __restrict__ Wc, const float* __restrict__ Wo,
    const float* __restrict__ Why, const float* __restrict__ hinit,
    const float* __restrict__ cinit,
    unsigned short* __restrict__ Wp, unsigned short* __restrict__ Whyp,
    unsigned short* __restrict__ hbf0, float* __restrict__ cbuf)
{
  long idx = (long)blockIdx.x * blockDim.x + threadIdx.x;
  const long NW = 1024L * 2048;
  const long NY = 512L * 512;
  const long NH = 64L * 512;
  const long NC = 64L * 512;
  if (idx < NW) {
    int e = idx & 7, l = (idx >> 3) & 63, kk = (idx >> 9) & 31;
    int Jc = (int)(idx >> 14);                   // 0..127
    int k = kk * 32 + (l >> 4) * 8 + e;          // 0..1023
    int col = Jc * 16 + (l & 15);                // 0..2047
    int gg = col >> 9, j = col & 511;
    const float* W = (gg == 0) ? Wf : (gg == 1) ? Wi : (gg == 2) ? Wc : Wo;
    Wp[idx] = (unsigned short)f2bfs(W[(long)k * 512 + j]);
  } else if (idx < NW + NY) {
    long q = idx - NW;
    int e = q & 7, l = (q >> 3) & 63, kk = (q >> 9) & 15;
    int J = (int)(q >> 13);
    int k = kk * 32 + (l >> 4) * 8 + e;
    int col = J * 16 + (l & 15);
    Whyp[q] = (unsigned short)f2bfs(Why[(long)k * 512 + col]);
  } else if (idx < NW + NY + NH) {
    long q = idx - NW - NY;
    hbf0[q] = (unsigned short)f2bfs(hinit[q]);
  } else if (idx < NW + NY + NH + NC) {
    long q = idx - NW - NY - NH;
    cbuf[q] = cinit[q];
  }
}

// ---------------------------------------------------------------------------
// x fp32 -> bf16 streaming conversion.
// ---------------------------------------------------------------------------
__global__ __launch_bounds__(256) void xconv(
    const float* __restrict__ x, unsigned short* __restrict__ xb)
{
  long i = ((long)blockIdx.x * 256 + threadIdx.x) * 8;
  float4 a = *(const float4*)(x + i);
  float4 b = *(const float4*)(x + i + 4);
  bf16x8 v;
  v[0] = f2bfs(a.x); v[1] = f2bfs(a.y); v[2] = f2bfs(a.z); v[3] = f2bfs(a.w);
  v[4] = f2bfs(b.x); v[5] = f2bfs(b.y); v[6] = f2bfs(b.z); v[7] = f2bfs(b.w);
  *(bf16x8*)(xb + i) = v;
}

// ---------------------------------------------------------------------------
// ONE LSTM timestep. Launched 1024x as sequential graph nodes; the kernel
// boundary provides the grid barrier + cross-XCD coherence (runtime-managed).
// Plain cached memory ops only — no sc bits, no atomics, no polls.
// Math identical to the round-4 proven path (absmax 3.9e-3).
// Block jb owns h-cols [16jb,16jb+16) x all 4 gates for all 64 batch rows.
// ---------------------------------------------------------------------------
template<bool X16>
__global__ __launch_bounds__(256) void lstm_step(
    const void* __restrict__ xv,      // (B,T,D) bf16 or fp32
    const float* __restrict__ bf_, const float* __restrict__ bi_,
    const float* __restrict__ bc_, const float* __restrict__ bo_,
    const unsigned short* __restrict__ Wp,
    const unsigned short* __restrict__ hin,   // (B,H) bf16  h_{t-1}
    unsigned short* __restrict__ hout,        // (B,H) bf16  h_t
    float* __restrict__ cbuf,                 // (B,H) fp32  c state
    unsigned short* __restrict__ hs,          // (T,B,H) bf16 history
    float* __restrict__ tail,                 // h_fin, c_fin (written at t=T-1)
    int t)
{
  const int jb   = blockIdx.x;
  const int tid  = threadIdx.x;
  const int wv   = tid >> 6;
  const int lane = tid & 63;
  const int lrow = lane & 15;
  const int lkg  = lane >> 4;
  const int b_arow = wv * 16 + lrow;       // A-fragment row (batch index)
  const int jcol   = jb * 16 + lrow;       // owned hidden unit (C/D col)
  const int b_cd0  = wv * 16 + lkg * 4;    // C/D row base (batch index)

  // ---- issue all A-operand loads first (h from L2, x from L2/HBM) ----
  const unsigned short* hrow = hin + (long)b_arow * H_ + lkg * 8;
  bf16x8 hf[16];
  #pragma unroll
  for (int kk = 0; kk < 16; ++kk) hf[kk] = *(const bf16x8*)(hrow + kk * 32);

  bf16x8 xf[16];
  float4 xr[32];
  if constexpr (X16) {
    const unsigned short* xt = (const unsigned short*)xv
        + (long)b_arow * T_ * D_ + (long)t * D_ + lkg * 8;
    #pragma unroll
    for (int kk = 0; kk < 16; ++kk) xf[kk] = *(const bf16x8*)(xt + kk * 32);
  } else {
    const float* xt = (const float*)xv
        + (long)b_arow * T_ * D_ + (long)t * D_ + lkg * 8;
    #pragma unroll
    for (int kk = 0; kk < 16; ++kk) {
      xr[2*kk]   = *(const float4*)(xt + kk * 32);
      xr[2*kk+1] = *(const float4*)(xt + kk * 32 + 4);
    }
  }

  // ---- biases + cell state ----
  const float vbf = bf_[jcol], vbi = bi_[jcol], vbc = bc_[jcol], vbo = bo_[jcol];
  float c0 = cbuf[(long)(b_cd0 + 0) * H_ + jcol];
  float c1 = cbuf[(long)(b_cd0 + 1) * H_ + jcol];
  float c2 = cbuf[(long)(b_cd0 + 2) * H_ + jcol];
  float c3 = cbuf[(long)(b_cd0 + 3) * H_ + jcol];

  const unsigned short* w0 = Wp + (long)(0 * 32 + jb) * 32 * 512 + lane * 8;
  const unsigned short* w1 = Wp + (long)(1 * 32 + jb) * 32 * 512 + lane * 8;
  const unsigned short* w2 = Wp + (long)(2 * 32 + jb) * 32 * 512 + lane * 8;
  const unsigned short* w3 = Wp + (long)(3 * 32 + jb) * 32 * 512 + lane * 8;

  f32x4 af = {vbf, vbf, vbf, vbf};
  f32x4 ai = {vbi, vbi, vbi, vbi};
  f32x4 ac = {vbc, vbc, vbc, vbc};
  f32x4 ao = {vbo, vbo, vbo, vbo};

  #pragma unroll
  for (int kk = 0; kk < 16; ++kk) {
    bf16x8 ah = hf[kk];
    af = __builtin_amdgcn_mfma_f32_16x16x32_bf16(ah, *(const bf16x8*)(w0 + kk * 512), af, 0, 0, 0);
    ai = __builtin_amdgcn_mfma_f32_16x16x32_bf16(ah, *(const bf16x8*)(w1 + kk * 512), ai, 0, 0, 0);
    ac = __builtin_amdgcn_mfma_f32_16x16x32_bf16(ah, *(const bf16x8*)(w2 + kk * 512), ac, 0, 0, 0);
    ao = __builtin_amdgcn_mfma_f32_16x16x32_bf16(ah, *(const bf16x8*)(w3 + kk * 512), ao, 0, 0, 0);
    bf16x8 ax;
    if constexpr (X16) {
      ax = xf[kk];
    } else {
      float4 xa = xr[2*kk], xb2 = xr[2*kk+1];
      ax[0]=f2bfs(xa.x); ax[1]=f2bfs(xa.y); ax[2]=f2bfs(xa.z); ax[3]=f2bfs(xa.w);
      ax[4]=f2bfs(xb2.x); ax[5]=f2bfs(xb2.y); ax[6]=f2bfs(xb2.z); ax[7]=f2bfs(xb2.w);
    }
    const int k2 = kk + 16;
    af = __builtin_amdgcn_mfma_f32_16x16x32_bf16(ax, *(const bf16x8*)(w0 + k2 * 512), af, 0, 0, 0);
    ai = __builtin_amdgcn_mfma_f32_16x16x32_bf16(ax, *(const bf16x8*)(w1 + k2 * 512), ai, 0, 0, 0);
    ac = __builtin_amdgcn_mfma_f32_16x16x32_bf16(ax, *(const bf16x8*)(w2 + k2 * 512), ac, 0, 0, 0);
    ao = __builtin_amdgcn_mfma_f32_16x16x32_bf16(ax, *(const bf16x8*)(w3 + k2 * 512), ao, 0, 0, 0);
  }

  // ---- gates + state update (C/D: col=lane&15, row=(lane>>4)*4+i) ----
  #pragma unroll
  for (int i2 = 0; i2 < 4; ++i2) {
    float fg = sigmoid_f(af[i2]);
    float ig = sigmoid_f(ai[i2]);
    float gg = tanh_f(ac[i2]);
    float og = sigmoid_f(ao[i2]);
    float cN = (i2 == 0) ? c0 : (i2 == 1) ? c1 : (i2 == 2) ? c2 : c3;
    cN = fg * cN + ig * gg;
    float hv = og * tanh_f(cN);
    if (i2 == 0) c0 = cN; else if (i2 == 1) c1 = cN; else if (i2 == 2) c2 = cN; else c3 = cN;
    unsigned short hb = (unsigned short)f2bfs(hv);
    int brow = b_cd0 + i2;
    cbuf[(long)brow * H_ + jcol] = cN;
    hout[(long)brow * H_ + jcol] = hb;
    __builtin_nontemporal_store(hb, hs + ((long)t * B_ + brow) * H_ + jcol);
    if (t == T_ - 1) {
      tail[(long)brow * H_ + jcol] = hv;                    // h_fin
      tail[(long)B_ * H_ + (long)brow * H_ + jcol] = cN;    // c_fin
    }
  }
}

// ---------------------------------------------------------------------------
// Output projection: out(B,T,O) = hs(T,B,H) @ W_hy + b_hy.  (round-1 proven)
// ---------------------------------------------------------------------------
__global__ __launch_bounds__(512) void out_proj(
    const unsigned short* __restrict__ hs,
    const unsigned short* __restrict__ Whyp,
    const float* __restrict__ bhy,
    float* __restrict__ out)
{
  const int tid  = threadIdx.x;
  const int wv   = tid >> 6;
  const int lane = tid & 63;
  const int lrow = lane & 15;
  const int lkg  = lane >> 4;
  const int mg = wv >> 2;
  const int ng = wv & 3;
  const long mbase = (long)blockIdx.x * 128 + mg * 64;

  f32x4 acc[4][8];
  #pragma unroll
  for (int mt = 0; mt < 4; ++mt)
    #pragma unroll
    for (int nt = 0; nt < 8; ++nt) {
      float b = bhy[ng * 128 + nt * 16 + lrow];
      acc[mt][nt] = {b, b, b, b};
    }

  const unsigned short* arow = hs + (mbase + lrow) * 512 + lkg * 8;
  const unsigned short* bbas = Whyp + (long)(ng * 8) * 8192 + lane * 8;

  #pragma unroll
  for (int kk = 0; kk < 16; ++kk) {
    bf16x8 a0 = *(const bf16x8*)(arow + 0 * 8192 + kk * 32);
    bf16x8 a1 = *(const bf16x8*)(arow + 1 * 8192 + kk * 32);
    bf16x8 a2 = *(const bf16x8*)(arow + 2 * 8192 + kk * 32);
    bf16x8 a3 = *(const bf16x8*)(arow + 3 * 8192 + kk * 32);
    #pragma unroll
    for (int nt = 0; nt < 8; ++nt) {
      bf16x8 bv = *(const bf16x8*)(bbas + nt * 8192 + kk * 512);
      acc[0][nt] = __builtin_amdgcn_mfma_f32_16x16x32_bf16(a0, bv, acc[0][nt], 0, 0, 0);
      acc[1][nt] = __builtin_amdgcn_mfma_f32_16x16x32_bf16(a1, bv, acc[1][nt], 0, 0, 0);
      acc[2][nt] = __builtin_amdgcn_mfma_f32_16x16x32_bf16(a2, bv, acc[2][nt], 0, 0, 0);
      acc[3][nt] = __builtin_amdgcn_mfma_f32_16x16x32_bf16(a3, bv, acc[3][nt], 0, 0, 0);
    }
  }

  #pragma unroll
  for (int mt = 0; mt < 4; ++mt) {
    #pragma unroll
    for (int i2 = 0; i2 < 4; ++i2) {
      long m = mbase + mt * 16 + lkg * 4 + i2;
      long t = m >> 6, b = m & 63;
      float* orow = out + (b * 1024 + t) * 512;
      #pragma unroll
      for (int nt = 0; nt < 8; ++nt)
        orow[ng * 128 + nt * 16 + lrow] = acc[mt][nt][i2];
    }
  }
}

// ---------------------------------------------------------------------------
extern "C" void kernel_launch(void* const* d_in, const int* in_sizes, int n_in,
                              void* d_out, int out_size, void* d_ws, size_t ws_size,
                              hipStream_t stream) {
  const float* x      = (const float*)d_in[0];
  const float* h_init = (const float*)d_in[1];
  const float* c_init = (const float*)d_in[2];
  const float* W_f = (const float*)d_in[3];
  const float* b_f = (const float*)d_in[4];
  const float* W_i = (const float*)d_in[5];
  const float* b_i = (const float*)d_in[6];
  const float* W_c = (const float*)d_in[7];
  const float* b_c = (const float*)d_in[8];
  const float* W_o = (const float*)d_in[9];
  const float* b_o = (const float*)d_in[10];
  const float* W_hy = (const float*)d_in[11];
  const float* b_hy = (const float*)d_in[12];
  float* out = (float*)d_out;

  // ws layout (bytes)
  const size_t WP_OFF   = 0;                          // 4 MB
  const size_t WHYP_OFF = 4u << 20;                   // 512 KB
  const size_t HBF0_OFF = WHYP_OFF + (512u << 10);    // 64 KB
  const size_t HBF1_OFF = HBF0_OFF + (64u << 10);     // 64 KB
  const size_t CB_OFF   = HBF1_OFF + (64u << 10);     // 128 KB fp32 c-state
  const size_t XB_OFF   = 8u << 20;                   // 64 MB (big path only)
  const size_t HS_BYTES = (size_t)T_ * B_ * H_ * 2;   // 64 MB
  const size_t XB_BYTES = (size_t)B_ * T_ * D_ * 2;   // 64 MB
  const size_t NEED_SMALL = (8u << 20) + HS_BYTES;
  const size_t NEED_BIG   = XB_OFF + XB_BYTES + HS_BYTES;
  if (ws_size < NEED_SMALL) return;
  const bool big = (ws_size >= NEED_BIG);

  unsigned char* w = (unsigned char*)d_ws;
  unsigned short* Wp   = (unsigned short*)(w + WP_OFF);
  unsigned short* Whyp = (unsigned short*)(w + WHYP_OFF);
  unsigned short* hbf0 = (unsigned short*)(w + HBF0_OFF);
  unsigned short* hbf1 = (unsigned short*)(w + HBF1_OFF);
  float*          cbuf = (float*)(w + CB_OFF);
  unsigned short* xb   = (unsigned short*)(w + XB_OFF);
  unsigned short* hs   = (unsigned short*)(w + (big ? XB_OFF + XB_BYTES : (size_t)(8u << 20)));

  // 1) pack weights + h_init/c_init staging (re-runs every call: stateless)
  const long total = 1024L * 2048 + 512L * 512 + 64L * 512 + 64L * 512;
  int pgrid = (int)((total + 255) / 256);
  pack_setup<<<pgrid, 256, 0, stream>>>(W_f, W_i, W_c, W_o, W_hy, h_init, c_init,
                                        Wp, Whyp, hbf0, cbuf);

  // 2) optional x -> bf16 preconversion
  if (big) {
    const long nx = (long)B_ * T_ * D_;
    int xgrid = (int)(nx / (256 * 8));
    xconv<<<xgrid, 256, 0, stream>>>(x, xb);
  }

  // 3) recurrence: one kernel per timestep; kernel boundary = grid barrier
  float* tail = out + (size_t)B_ * T_ * O_;
  for (int t = 0; t < T_; ++t) {
    const unsigned short* hin = (t & 1) ? hbf1 : hbf0;
    unsigned short*       hout = (t & 1) ? hbf0 : hbf1;
    if (big) {
      lstm_step<true><<<NBLK, 256, 0, stream>>>(
          xb, b_f, b_i, b_c, b_o, Wp, hin, hout, cbuf, hs, tail, t);
    } else {
      lstm_step<false><<<NBLK, 256, 0, stream>>>(
          x, b_f, b_i, b_c, b_o, Wp, hin, hout, cbuf, hs, tail, t);
    }
  }

  // 4) output projection
  out_proj<<<512, 512, 0, stream>>>(hs, Whyp, b_hy, out);
}